// Round 13
// baseline (268.996 us; speedup 1.0000x reference)
//
#include <hip/hip_runtime.h>
#include <math.h>

#define KK 15
#define K1 16
#define NN 4096
#define BSZ 128
#define NBLK 256       // 2 blocks per batch: (b, b+128) pair, split data phases
#define NT 512
#define RPT 8          // rows per thread = NN/NT (loads + loop: all 8)
#define RPTD 4         // data-phase rows per thread (the block's half)
#define NPAIR 4        // packed row pairs per thread (loop)
#define NW 8           // waves per block
#define EPSI 0.1f
#define SMALLC 1e-20f
#define NITER 100      // cap; conv exit fires after only a few iters (R11 evidence)
#define OUT_A_ELEMS (BSZ * NN * KK)
#define TS 20          // wbufT row stride in floats (2-way bank alias only, free)
#define CONV_REL 2e-6f

// ---- workspace layout (uint32 words) ----
// header [0..15]: [0]=max_enc [1]=neg [2]=norm f32 [3]=arrive [4]=done [5]=min_enc_compl
#define SLOTW 128
#define WS_WORDS (16 + BSZ * SLOTW)
#define SO_CTOP 0      // pair counters
#define SO_CCOL 1
#define SO_CWARM 2
#define SO_TOPK 8      // 2 x 16 floats (top-15 desc + -inf pad)
#define SO_COL  40     // 2 x 16 floats (Gamma0 colsum partials)
#define SO_WCOL 72     // 2 x 16 floats (warm bb colsum partials)
#define SO_RD   104    // 2 x 8 floats (warm rowdot partials)

typedef __attribute__((ext_vector_type(2))) float f2;
typedef __attribute__((ext_vector_type(2))) unsigned u2v;
__device__ __forceinline__ f2 pk_fma(f2 a, f2 b, f2 c){
  return __builtin_elementwise_fma(a, b, c);
}

// ---------- sortable float <-> uint encoding for atomic min/max ----------
__device__ __forceinline__ unsigned enc_f32(float f){
  unsigned u = __float_as_uint(f);
  return (u & 0x80000000u) ? ~u : (u | 0x80000000u);
}
__device__ __forceinline__ float dec_f32(unsigned e){
  unsigned u = (e & 0x80000000u) ? (e ^ 0x80000000u) : ~e;
  return __uint_as_float(u);
}

// ---------- DPP cross-lane mov (VALU pipe, not DS) ----------
template<int CTRL>
__device__ __forceinline__ float dpp_movf(float x){
  return __uint_as_float((unsigned)__builtin_amdgcn_update_dpp(
      (int)0, (int)__float_as_uint(x), CTRL, 0xF, 0xF, true));
}

__device__ __forceinline__ float bcast_lane0(float x){
  return __uint_as_float((unsigned)__builtin_amdgcn_readlane(
      (int)__float_as_uint(x), 0));
}

__device__ __forceinline__ float xsum16(float r){
#if __has_builtin(__builtin_amdgcn_permlane16_swap)
  u2v s = __builtin_amdgcn_permlane16_swap(__float_as_uint(r), __float_as_uint(r), false, false);
  return __uint_as_float(s.x) + __uint_as_float(s.y);
#else
  return r + __shfl_xor(r, 16);
#endif
}
__device__ __forceinline__ float xsum32(float r){
#if __has_builtin(__builtin_amdgcn_permlane32_swap)
  u2v s = __builtin_amdgcn_permlane32_swap(__float_as_uint(r), __float_as_uint(r), false, false);
  return __uint_as_float(s.x) + __uint_as_float(s.y);
#else
  return r + __shfl_xor(r, 32);
#endif
}

// 16-lane-group sum -- 4 DPP adds, no DS
__device__ __forceinline__ float sum16_all(float v){
  v += dpp_movf<0x128>(v);   // row_ror:8
  v += dpp_movf<0x124>(v);   // row_ror:4
  v += dpp_movf<0x4E>(v);    // quad_perm xor2
  v += dpp_movf<0xB1>(v);    // quad_perm xor1
  return v;
}
// full 64-lane sum in every lane -- all VALU, no DS
__device__ __forceinline__ float full64_sum(float v){
  return xsum32(xsum16(sum16_all(v)));
}

// ---------- 16-column lane-fold reduction (DPP-based) ----------
__device__ __forceinline__ int fold_col(int lane){
  int l = lane & 15;
  return ((l & 1) << 3) | ((l & 2) << 1) | ((l & 8) >> 2) | ((l & 4) >> 2);
}

__device__ __forceinline__ float wave_fold16(const float p[K1], int lane){
  float a[8];
  {
    const bool hi = (lane & 1) != 0;
    #pragma unroll
    for (int j = 0; j < 8; ++j){
      float send = hi ? p[j] : p[j + 8];
      float keep = hi ? p[j + 8] : p[j];
      a[j] = keep + dpp_movf<0xB1>(send);
    }
  }
  float bq[4];
  {
    const bool hi = (lane & 2) != 0;
    #pragma unroll
    for (int j = 0; j < 4; ++j){
      float send = hi ? a[j] : a[j + 4];
      float keep = hi ? a[j + 4] : a[j];
      bq[j] = keep + dpp_movf<0x4E>(send);
    }
  }
  float cq[2];
  {
    const bool hi = (lane & 8) != 0;
    float s0 = hi ? bq[0] : bq[2];
    float s1 = hi ? bq[1] : bq[3];
    float k0 = hi ? bq[2] : bq[0];
    float k1 = hi ? bq[3] : bq[1];
    cq[0] = k0 + dpp_movf<0x128>(s0);
    cq[1] = k1 + dpp_movf<0x128>(s1);
  }
  float r;
  {
    const bool hi = (lane & 4) != 0;
    float send = hi ? cq[0] : cq[1];
    float keep = hi ? cq[1] : cq[0];
    r = keep + __shfl_xor(send, 4);
  }
  r = xsum16(r);
  r = xsum32(r);
  return r;
}

__device__ __forceinline__ void block_fold16(const float p[K1], float* wb, float* tb,
                                             int lane, int wv, int tid){
  float r = wave_fold16(p, lane);
  if (lane < 16) wb[wv * K1 + fold_col(lane)] = r;
  __syncthreads();
  if (tid < 16){
    float t = 0.0f;
    #pragma unroll
    for (int q = 0; q < NW; ++q) t += wb[q * K1 + tid];
    tb[tid] = t;
  }
  __syncthreads();
}

// ---------- pair sync: publish -> count to 2 -> consume ----------
__device__ __forceinline__ void pair_sync(unsigned* ctr, int tid){
  __threadfence();             // push this thread's prior global stores
  __syncthreads();             // all writers fenced
  if (tid == 0){
    __hip_atomic_fetch_add(ctr, 1u, __ATOMIC_RELEASE, __HIP_MEMORY_SCOPE_AGENT);
    while (__hip_atomic_load(ctr, __ATOMIC_ACQUIRE, __HIP_MEMORY_SCOPE_AGENT) < 2u)
      __builtin_amdgcn_s_sleep(1);
  }
  __syncthreads();
}

__global__ __launch_bounds__(NT, 2) void k_main(
    const float* __restrict__ scores, const float* __restrict__ taup,
    const float* __restrict__ w1, const float* __restrict__ w2,
    float* __restrict__ out, unsigned* __restrict__ ws){
  const int bid = blockIdx.x;
  const int b   = bid & (BSZ - 1);   // batch
  const int half= bid >> 7;          // 0 or 1; pair (b, b+128) -> same XCD (round-robin)
  const int JB  = 4 * half;          // data-phase row-slot base
  const int tid = threadIdx.x;
  const int lane = tid & 63;
  const int wv = tid >> 6;
  unsigned* slot = ws + 16 + b * SLOTW;
  float* slotf = (float*)slot;

  __shared__ float tk[KK];
  __shared__ float cands[NW * KK];
  __shared__ __align__(16) float cbuf[K1];
  __shared__ float wbuf[NW * K1];
  __shared__ float wrow[NW * 5];
  __shared__ __align__(16) float xbuf[K1];
  __shared__ __align__(16) float bbcol[K1];
  __shared__ float xv5[8];
  __shared__ __align__(16) float wbufT[2][K1 * TS];
  __shared__ float rv[NW];
  __shared__ float rmn[NW];
  __shared__ unsigned sng[NW];
  __shared__ float statb[4];

  // ---- load all 8 rows of this batch (loop needs full row; phases use half) ----
  float raw[RPT];
  #pragma unroll
  for (int j = 0; j < RPT; ++j) raw[j] = scores[(size_t)b * NN + tid + NT * j];

  // ---- fused global min/max/neg + device spin-barrier (256 blocks) ----
  {
    float mx = -INFINITY, mn = INFINITY; unsigned neg = 0u;
    #pragma unroll
    for (int j = 0; j < RPT; ++j){
      float v = raw[j];
      mx = fmaxf(mx, v);
      if (v == -INFINITY) neg = 1u; else mn = fminf(mn, v);
    }
    #pragma unroll
    for (int off = 32; off; off >>= 1){
      mx = fmaxf(mx, __shfl_xor(mx, off));
      mn = fminf(mn, __shfl_xor(mn, off));
      neg |= (unsigned)__shfl_xor((int)neg, off);
    }
    if (lane == 0){ rv[wv] = mx; rmn[wv] = mn; sng[wv] = neg; }
    __syncthreads();
    if (tid == 0){
      for (int q = 1; q < NW; ++q){
        mx = fmaxf(mx, rv[q]); mn = fminf(mn, rmn[q]); neg |= sng[q];
      }
      atomicMax(&ws[0], enc_f32(mx));
      atomicMax(&ws[5], ~enc_f32(mn));          // complemented min (init 0)
      if (neg) atomicOr(&ws[1], 1u);
      __threadfence();
      atomicAdd(&ws[3], 1u);
      while (__hip_atomic_load(&ws[3], __ATOMIC_ACQUIRE, __HIP_MEMORY_SCOPE_AGENT) < (unsigned)NBLK)
        __builtin_amdgcn_s_sleep(2);
      statb[0] = dec_f32(__hip_atomic_load(&ws[0], __ATOMIC_RELAXED, __HIP_MEMORY_SCOPE_AGENT));
      statb[1] = dec_f32(~__hip_atomic_load(&ws[5], __ATOMIC_RELAXED, __HIP_MEMORY_SCOPE_AGENT));
      statb[2] = __hip_atomic_load(&ws[1], __ATOMIC_RELAXED, __HIP_MEMORY_SCOPE_AGENT) ? 1.0f : 0.0f;
    }
    __syncthreads();
  }

  const float smax = statb[0];
  const float smin_raw = statb[1];
  const bool has_neg = statb[2] != 0.0f;
  const float filled = smin_raw - (smax - smin_raw);
  const float smin_eff = has_neg ? filled : smin_raw;
  const float cmax = fmaxf(fmaxf(smin_eff * smin_eff, smax * smax),
                           fmaxf((smin_eff - 15.0f) * (smin_eff - 15.0f),
                                 (smax - 15.0f) * (smax - 15.0f)));
  const float cinv = 1.0f / cmax;
  const float tauv = taup[0];
  const float invtau = 1.0f / tauv;
  const float inv_n = 1.0f / (float)NN;

  // ---- fixed s values: register-resident (all 8) ----
  float sv[RPT];
  #pragma unroll
  for (int j = 0; j < RPT; ++j){
    float v = raw[j]; if (v == -INFINITY) v = filled;
    sv[j] = v;
  }

  // ---- top-15 of THIS HALF (4 slots/lane), then block merge, then pair merge ----
  {
    float lv[RPTD];
    #pragma unroll
    for (int j = 0; j < RPTD; ++j) lv[j] = sv[JB + j];
    #pragma unroll
    for (int t = 0; t < KK; ++t){
      float bv = lv[0]; int bs = 0;
      #pragma unroll
      for (int j = 1; j < RPTD; ++j){ if (lv[j] > bv){ bv = lv[j]; bs = j; } }
      int bidx = (lane << 2) | bs;
      #pragma unroll
      for (int off = 32; off; off >>= 1){
        float ov = __shfl_xor(bv, off);
        int oi = __shfl_xor(bidx, off);
        if (ov > bv || (ov == bv && oi < bidx)){ bv = ov; bidx = oi; }
      }
      if ((bidx >> 2) == lane){
        int s = bidx & 3;
        #pragma unroll
        for (int j = 0; j < RPTD; ++j) if (j == s) lv[j] = -INFINITY;
      }
      if (lane == 0) cands[wv * KK + t] = bv;
    }
  }
  __syncthreads();
  if (wv == 0){
    float c0 = (lane < NW * KK) ? cands[lane] : -INFINITY;
    float c1 = (lane + 64 < NW * KK) ? cands[lane + 64] : -INFINITY;
    #pragma unroll
    for (int t = 0; t < KK; ++t){
      int sel = (c0 >= c1) ? 0 : 1;
      float bv = sel ? c1 : c0;
      int bidx = (lane << 1) | sel;
      #pragma unroll
      for (int off = 32; off; off >>= 1){
        float ov = __shfl_xor(bv, off);
        int oi = __shfl_xor(bidx, off);
        if (ov > bv || (ov == bv && oi < bidx)){ bv = ov; bidx = oi; }
      }
      if ((bidx >> 1) == lane){
        if ((bidx & 1) == 0) c0 = -INFINITY; else c1 = -INFINITY;
      }
      if (lane == 0) tk[t] = bv;
    }
  }
  __syncthreads();
  // publish half top-15 (desc, -inf pad), pair-merge canonically (A then B)
  if (tid < K1) slotf[SO_TOPK + half * K1 + tid] = (tid < KK) ? tk[tid] : -INFINITY;
  pair_sync(&slot[SO_CTOP], tid);
  if (tid == 0){
    const float* ga = slotf + SO_TOPK;
    const float* gb = slotf + SO_TOPK + K1;
    int ia = 0, ib = 0;
    #pragma unroll
    for (int t = 0; t < KK; ++t){
      float va = ga[ia], vb = gb[ib];
      if (va >= vb){ tk[t] = va; ++ia; } else { tk[t] = vb; ++ib; }
    }
  }
  __syncthreads();

  // ---- Gamma0 column sums over THIS HALF, pair-added ----
  {
    float p[K1];
    float tkr[KK];
    #pragma unroll
    for (int c = 0; c < KK; ++c) tkr[c] = tk[c];
    #pragma unroll
    for (int c = 0; c < K1; ++c) p[c] = 0.0f;
    #pragma unroll
    for (int j = 0; j < RPTD; ++j){
      float si = sv[JB + j];
      #pragma unroll
      for (int c = 0; c < KK; ++c){
        float z = fabsf(tkr[c] - si) * invtau;
        float raw1 = __builtin_amdgcn_rcpf(1.0f + __expf(z)) + SMALLC;
        p[c] += raw1;
      }
    }
    block_fold16(p, wbuf, cbuf, lane, wv, tid);
  }
  if (tid < K1) slotf[SO_COL + half * K1 + tid] = cbuf[tid];
  pair_sync(&slot[SO_CCOL], tid);
  if (tid < K1) cbuf[tid] = slotf[SO_COL + tid] + slotf[SO_COL + K1 + tid];
  __syncthreads();

  // ---- warm start (separable w2) over THIS HALF, pair-added ----
  float colinv_n[KK];
  {
    float pcol[K1];
    float pr0 = 0.0f, pr1 = 0.0f, pr2 = 0.0f, pr3 = 0.0f, pr4 = 0.0f;
    float tkr[KK];
    #pragma unroll
    for (int c = 0; c < KK; ++c){
      tkr[c] = tk[c];
      colinv_n[c] = (1.0f / cbuf[c]) * inv_n;
    }
    #pragma unroll
    for (int c = 0; c < K1; ++c) pcol[c] = 0.0f;
    #pragma unroll
    for (int j = 0; j < RPTD; ++j){
      int i = tid + NT * (JB + j);
      float si = sv[JB + j];
      float bb[K1];
      float rowpart = 0.0f;
      #pragma unroll
      for (int c = 0; c < KK; ++c){
        float d = si - (float)(KK - c);
        float Cc = d * d * cinv;
        float z = fabsf(tkr[c] - si) * invtau;
        float raw1 = __builtin_amdgcn_rcpf(1.0f + __expf(z)) + SMALLC;
        float g0 = raw1 * colinv_n[c];
        rowpart += g0;
        bb[c] = Cc + EPSI * __logf(g0);
      }
      {
        float Cc = si * si * cinv;
        float g0l = fminf(fmaxf(inv_n - rowpart, SMALLC), 1.0f - SMALLC);
        bb[KK] = Cc + EPSI * __logf(g0l);
      }
      float rs = 0.0f;
      #pragma unroll
      for (int c = 0; c < K1; ++c){ pcol[c] += bb[c]; rs += bb[c]; }
      const float* w1r = w1 + (size_t)i * 5;
      pr0 = fmaf(w1r[0], rs, pr0);
      pr1 = fmaf(w1r[1], rs, pr1);
      pr2 = fmaf(w1r[2], rs, pr2);
      pr3 = fmaf(w1r[3], rs, pr3);
      pr4 = fmaf(w1r[4], rs, pr4);
    }
    float rcol = wave_fold16(pcol, lane);
    float r0 = full64_sum(pr0);
    float r1 = full64_sum(pr1);
    float r2 = full64_sum(pr2);
    float r3 = full64_sum(pr3);
    float r4 = full64_sum(pr4);
    if (lane < 16) wbuf[wv * K1 + fold_col(lane)] = rcol;
    if (lane == 16) wrow[wv * 5 + 0] = r0;
    if (lane == 17) wrow[wv * 5 + 1] = r1;
    if (lane == 18) wrow[wv * 5 + 2] = r2;
    if (lane == 19) wrow[wv * 5 + 3] = r3;
    if (lane == 20) wrow[wv * 5 + 4] = r4;
    __syncthreads();
    if (tid < 16){
      float t = 0.0f;
      #pragma unroll
      for (int q = 0; q < NW; ++q) t += wbuf[q * K1 + tid];
      bbcol[tid] = t;
    } else if (tid < 21){
      int r = tid - 16;
      float t = 0.0f;
      #pragma unroll
      for (int q = 0; q < NW; ++q) t += wrow[q * 5 + r];
      xbuf[r] = t;
    }
    __syncthreads();
    // publish half partials, pair-add canonically
    if (tid < K1) slotf[SO_WCOL + half * K1 + tid] = bbcol[tid];
    else if (tid < K1 + 5) slotf[SO_RD + half * 8 + (tid - K1)] = xbuf[tid - K1];
    pair_sync(&slot[SO_CWARM], tid);
    if (tid < K1) bbcol[tid] = slotf[SO_WCOL + tid] + slotf[SO_WCOL + K1 + tid];
    else if (tid < K1 + 5){
      int r = tid - K1;
      xbuf[r] = slotf[SO_RD + r] + slotf[SO_RD + 8 + r];
    }
    __syncthreads();
    if (tid < 5){
      float xr = xbuf[tid];
      #pragma unroll
      for (int c = 0; c < KK; ++c)
        xr = fmaf(w1[(size_t)(NN + c) * 5 + tid], bbcol[c], xr);
      xv5[tid] = xr;
    }
    __syncthreads();
  }

  // ---- vt init (identical on both halves: same merged inputs) ----
  float vt[K1];
  {
    float xv[5];
    #pragma unroll
    for (int r = 0; r < 5; ++r) xv[r] = xv5[r];
    #pragma unroll
    for (int c = 0; c < KK; ++c){
      float g = 0.0f;
      #pragma unroll
      for (int r = 0; r < 5; ++r) g += xv[r] * w1[(size_t)(NN + c) * 5 + r];
      float Bc = expf(-10.0f * cinv * (float)((KK - c) * (KK - c)));
      vt[c] = Bc * expf(g * 10.0f);
    }
    vt[KK] = 1.0f;
  }

  // ---- x per row pair + power table (all 8 rows: loop runs on full row) ----
  f2 x2[NPAIR];
  #pragma unroll
  for (int q = 0; q < NPAIR; ++q){
    x2[q].x = expf(sv[2 * q] * (-20.0f * cinv));
    x2[q].y = expf(sv[2 * q + 1] * (-20.0f * cinv));
  }
  f2 xp[NPAIR][K1];
  #pragma unroll
  for (int q = 0; q < NPAIR; ++q){
    xp[q][0].x = 1.0f; xp[q][0].y = 1.0f;
    xp[q][1] = x2[q];
    #pragma unroll
    for (int c = 2; c < K1; ++c) xp[q][c] = xp[q][c - 1] * x2[q];
  }

  // ---- Sinkhorn: full-row loop, run redundantly by BOTH pair blocks ----
  // (bitwise-identical inputs -> identical vt/t2 sequence -> no sync needed)
  f2 t2[NPAIR];
  const float nmul = ((lane & 15) < KK) ? 1.0f : 4081.0f;
  float pv2 = 0.0f, pv1 = 0.0f;
  int pcnt = -1;
  #pragma unroll 1
  for (int it = 0; it < NITER; ++it){
    const int ph = it & 1;
    #pragma unroll
    for (int q = 0; q < NPAIR; ++q){
      f2 h; h.x = vt[KK]; h.y = vt[KK];
      #pragma unroll
      for (int c = KK - 1; c >= 0; --c){
        f2 vc; vc.x = vt[c]; vc.y = vt[c];
        h = pk_fma(h, x2[q], vc);
      }
      t2[q].x = __builtin_amdgcn_rcpf(h.x);
      t2[q].y = __builtin_amdgcn_rcpf(h.y);
    }
    float p[K1];
    #pragma unroll
    for (int c = 0; c < K1; ++c){
      f2 s = t2[0] * xp[0][c];
      #pragma unroll
      for (int q = 1; q < NPAIR; ++q) s = pk_fma(t2[q], xp[q][c], s);
      p[c] = s.x + s.y;
    }
    float r = wave_fold16(p, lane);
    if (lane < 16) wbufT[ph][fold_col(lane) * TS + wv] = r;
    __syncthreads();
    float md = -1.0f;
    float wout = 0.0f;
    if (lane < 16){
      const float* wp = &wbufT[ph][lane * TS];
      float4 a4 = *(const float4*)wp;
      float4 b4 = *(const float4*)(wp + 4);
      float t = ((a4.x + a4.y) + (a4.z + a4.w)) + ((b4.x + b4.y) + (b4.z + b4.w));
      float wnew = nmul * __builtin_amdgcn_rcpf(t);
      md = fabsf(wnew - pv1) - CONV_REL * pv1;
      wout = wnew;
    }
    if (pcnt >= 1){
      float r1 = 0.0f, r2 = 0.0f;
      if (lane < 16){
        float winv = __builtin_amdgcn_rcpf(wout);
        r1 = (pv1 - pv2) * winv;
        r2 = (wout - pv1) * winv;
      }
      float s12 = full64_sum(r1 * r2);
      float s11 = full64_sum(r1 * r1);
      float s12b = bcast_lane0(s12);
      float s11b = bcast_lane0(s11);
      int anymove = __any((lane < 16) && (fabsf(r2) > 4.0f * CONV_REL));
      float fac = s12b * __builtin_amdgcn_rcpf(s11b - s12b);
      float acc = wout * (1.0f + r2 * fac);
      int okbr = (lane < 16) ? (acc > 0.1f * wout && acc < 10.0f * wout) : 1;
      int allbr = __all(okbr);
      if ((s12b > 0.0f) && (s12b < 0.97f * s11b) && anymove && allbr){
        if (lane < 16) wout = acc;
        pcnt = -1;
      }
    }
    pcnt++;
    pv2 = pv1; pv1 = wout;
    int conv = __all(md <= 0.0f);
    #pragma unroll
    for (int c = 0; c < K1; ++c)
      vt[c] = __uint_as_float((unsigned)__builtin_amdgcn_readlane(
                  (int)__float_as_uint(wout), c));
    if (conv) break;
  }

  // ---- epilogue: THIS HALF's rows only (q = 2*half, 2*half+1) ----
  float nrm = 0.0f;
  {
    float tkr[KK];
    #pragma unroll
    for (int c = 0; c < KK; ++c) tkr[c] = tk[c];
    #pragma unroll
    for (int qq = 0; qq < 2; ++qq){
      const int q = 2 * half + qq;
      #pragma unroll
      for (int e = 0; e < 2; ++e){
        int i = tid + NT * (2 * q + e);
        float si = sv[2 * q + e];
        float tin = (e ? t2[q].y : t2[q].x) * inv_n;
        float rowpart = 0.0f;
        float gamv[KK];
        float gaml;
        #pragma unroll
        for (int c = 0; c < KK; ++c){
          float xc = e ? xp[q][c].y : xp[q][c].x;
          float gam = (tin * xc) * vt[c];
          float z = fabsf(tkr[c] - si) * invtau;
          float raw1 = __builtin_amdgcn_rcpf(1.0f + __expf(z)) + SMALLC;
          float g0 = raw1 * colinv_n[c];
          rowpart += g0;
          float d = gam - g0;
          nrm += d * d;
          gamv[c] = gam * (float)NN;
        }
        {
          float xc = e ? xp[q][KK].y : xp[q][KK].x;
          gaml = (tin * xc) * vt[KK];
          float g0l = fminf(fmaxf(inv_n - rowpart, SMALLC), 1.0f - SMALLC);
          float d = gaml - g0l;
          nrm += d * d;
        }
        float* op = out + (size_t)(b * NN + i) * KK;
        #pragma unroll
        for (int c = 0; c < KK; ++c) op[c] = gamv[c];
      }
    }
  }
  #pragma unroll
  for (int off = 32; off; off >>= 1) nrm += __shfl_xor(nrm, off);
  if (lane == 0) rv[wv] = nrm;
  __syncthreads();
  if (tid == 0){
    float t = 0.0f;
    for (int q = 0; q < NW; ++q) t += rv[q];
    atomicAdd(reinterpret_cast<float*>(ws) + 2, t);
    __threadfence();
    unsigned prev = atomicAdd(&ws[4], 1u);
    if (prev == (unsigned)(NBLK - 1)){
      float n2 = __hip_atomic_load(reinterpret_cast<float*>(ws) + 2,
                                   __ATOMIC_RELAXED, __HIP_MEMORY_SCOPE_AGENT);
      out[OUT_A_ELEMS] = sqrtf(n2);
    }
  }
}

extern "C" void kernel_launch(void* const* d_in, const int* in_sizes, int n_in,
                              void* d_out, int out_size, void* d_ws, size_t ws_size,
                              hipStream_t stream){
  const float* scores = (const float*)d_in[0];
  const float* tau    = (const float*)d_in[1];
  const float* w1     = (const float*)d_in[2];  // (4111, 5) row-major
  const float* w2     = (const float*)d_in[3];  // (5, 65536) row-major (unused: separable identity)
  float* out = (float*)d_out;
  unsigned* ws = (unsigned*)d_ws;

  // zero header + all per-batch slots (counters must start at 0 each launch)
  hipMemsetAsync(ws, 0x00, WS_WORDS * 4, stream);

  k_main<<<NBLK, NT, 0, stream>>>(scores, tau, w1, w2, out, ws);
}

// Round 14
// 170.494 us; speedup vs baseline: 1.5777x; 1.5777x over previous
//
#include <hip/hip_runtime.h>
#include <math.h>

#define KK 15
#define K1 16
#define NN 4096
#define BSZ 128
#define NBLK 256       // pair (b, b+128): redundant prologue+loop, split epilogue, NO pair sync
#define NT 512
#define RPT 8          // rows per thread = NN/NT
#define NPAIR 4        // packed row pairs per thread (loop: all 8 rows)
#define NW 8           // waves per block
#define EPSI 0.1f
#define SMALLC 1e-20f
#define NITER 100      // cap; conv exit fires after only a few iters (R11 evidence)
#define OUT_A_ELEMS (BSZ * NN * KK)
#define TS 20          // wbufT row stride in floats (2-way bank alias only, free)
#define CONV_REL 2e-6f

typedef __attribute__((ext_vector_type(2))) float f2;
typedef __attribute__((ext_vector_type(2))) unsigned u2v;
__device__ __forceinline__ f2 pk_fma(f2 a, f2 b, f2 c){
  return __builtin_elementwise_fma(a, b, c);
}

// ---------- sortable float <-> uint encoding for atomic min/max ----------
// max: enc as-is. min: stored COMPLEMENTED so the all-zero init works for both.
__device__ __forceinline__ unsigned enc_f32(float f){
  unsigned u = __float_as_uint(f);
  return (u & 0x80000000u) ? ~u : (u | 0x80000000u);
}
__device__ __forceinline__ float dec_f32(unsigned e){
  unsigned u = (e & 0x80000000u) ? (e ^ 0x80000000u) : ~e;
  return __uint_as_float(u);
}

// ws layout (uint32): [0]=max_enc(0) [1]=neg_flag(0) [2]=norm^2 f32(0)
//                     [3]=arrive(0) [4]=done(0) [5]=min_enc_complement(0)

// ---------- DPP cross-lane mov (VALU pipe, not DS) ----------
template<int CTRL>
__device__ __forceinline__ float dpp_movf(float x){
  return __uint_as_float((unsigned)__builtin_amdgcn_update_dpp(
      (int)0, (int)__float_as_uint(x), CTRL, 0xF, 0xF, true));
}

__device__ __forceinline__ float bcast_lane0(float x){
  return __uint_as_float((unsigned)__builtin_amdgcn_readlane(
      (int)__float_as_uint(x), 0));
}

__device__ __forceinline__ float xsum16(float r){
#if __has_builtin(__builtin_amdgcn_permlane16_swap)
  u2v s = __builtin_amdgcn_permlane16_swap(__float_as_uint(r), __float_as_uint(r), false, false);
  return __uint_as_float(s.x) + __uint_as_float(s.y);
#else
  return r + __shfl_xor(r, 16);
#endif
}
__device__ __forceinline__ float xsum32(float r){
#if __has_builtin(__builtin_amdgcn_permlane32_swap)
  u2v s = __builtin_amdgcn_permlane32_swap(__float_as_uint(r), __float_as_uint(r), false, false);
  return __uint_as_float(s.x) + __uint_as_float(s.y);
#else
  return r + __shfl_xor(r, 32);
#endif
}

// 16-lane-group sum -- 4 DPP adds, no DS
__device__ __forceinline__ float sum16_all(float v){
  v += dpp_movf<0x128>(v);   // row_ror:8
  v += dpp_movf<0x124>(v);   // row_ror:4
  v += dpp_movf<0x4E>(v);    // quad_perm xor2
  v += dpp_movf<0xB1>(v);    // quad_perm xor1
  return v;
}
// full 64-lane sum in every lane -- all VALU, no DS
__device__ __forceinline__ float full64_sum(float v){
  return xsum32(xsum16(sum16_all(v)));
}

// ---------- 16-column lane-fold reduction (DPP-based) ----------
__device__ __forceinline__ int fold_col(int lane){
  int l = lane & 15;
  return ((l & 1) << 3) | ((l & 2) << 1) | ((l & 8) >> 2) | ((l & 4) >> 2);
}

__device__ __forceinline__ float wave_fold16(const float p[K1], int lane){
  float a[8];
  {
    const bool hi = (lane & 1) != 0;
    #pragma unroll
    for (int j = 0; j < 8; ++j){
      float send = hi ? p[j] : p[j + 8];
      float keep = hi ? p[j + 8] : p[j];
      a[j] = keep + dpp_movf<0xB1>(send);
    }
  }
  float bq[4];
  {
    const bool hi = (lane & 2) != 0;
    #pragma unroll
    for (int j = 0; j < 4; ++j){
      float send = hi ? a[j] : a[j + 4];
      float keep = hi ? a[j + 4] : a[j];
      bq[j] = keep + dpp_movf<0x4E>(send);
    }
  }
  float cq[2];
  {
    const bool hi = (lane & 8) != 0;
    float s0 = hi ? bq[0] : bq[2];
    float s1 = hi ? bq[1] : bq[3];
    float k0 = hi ? bq[2] : bq[0];
    float k1 = hi ? bq[3] : bq[1];
    cq[0] = k0 + dpp_movf<0x128>(s0);
    cq[1] = k1 + dpp_movf<0x128>(s1);
  }
  float r;
  {
    const bool hi = (lane & 4) != 0;
    float send = hi ? cq[0] : cq[1];
    float keep = hi ? cq[1] : cq[0];
    r = keep + __shfl_xor(send, 4);
  }
  r = xsum16(r);
  r = xsum32(r);
  return r;
}

__device__ __forceinline__ void block_fold16(const float p[K1], float* wb, float* tb,
                                             int lane, int wv, int tid){
  float r = wave_fold16(p, lane);
  if (lane < 16) wb[wv * K1 + fold_col(lane)] = r;
  __syncthreads();
  if (tid < 16){
    float t = 0.0f;
    #pragma unroll
    for (int q = 0; q < NW; ++q) t += wb[q * K1 + tid];
    tb[tid] = t;
  }
  __syncthreads();
}

__global__ __launch_bounds__(NT, 2) void k_main(
    const float* __restrict__ scores, const float* __restrict__ taup,
    const float* __restrict__ w1, const float* __restrict__ w2,
    float* __restrict__ out, unsigned* __restrict__ ws){
  const int bid = blockIdx.x;
  const int b   = bid & (BSZ - 1);   // batch
  const int half= bid >> 7;          // 0/1: which epilogue half this block owns
  const int tid = threadIdx.x;
  const int lane = tid & 63;
  const int wv = tid >> 6;

  __shared__ float tk[KK];
  __shared__ float cands[NW * KK];
  __shared__ __align__(16) float cbuf[K1];
  __shared__ float wbuf[NW * K1];
  __shared__ float wrow[NW * 5];
  __shared__ __align__(16) float xbuf[K1];
  __shared__ __align__(16) float bbcol[K1];
  __shared__ float xv5[8];
  __shared__ __align__(16) float wbufT[2][K1 * TS];
  __shared__ float rv[NW];
  __shared__ float rmn[NW];
  __shared__ unsigned sng[NW];
  __shared__ float statb[4];

  // ---- load all 8 rows of this batch ----
  float raw[RPT];
  #pragma unroll
  for (int j = 0; j < RPT; ++j) raw[j] = scores[(size_t)b * NN + tid + NT * j];

  // ---- stats: reduce + PUBLISH (no spin yet) ----
  {
    float mx = -INFINITY, mn = INFINITY; unsigned neg = 0u;
    #pragma unroll
    for (int j = 0; j < RPT; ++j){
      float v = raw[j];
      mx = fmaxf(mx, v);
      if (v == -INFINITY) neg = 1u; else mn = fminf(mn, v);
    }
    #pragma unroll
    for (int off = 32; off; off >>= 1){
      mx = fmaxf(mx, __shfl_xor(mx, off));
      mn = fminf(mn, __shfl_xor(mn, off));
      neg |= (unsigned)__shfl_xor((int)neg, off);
    }
    if (lane == 0){ rv[wv] = mx; rmn[wv] = mn; sng[wv] = neg; }
    __syncthreads();
    if (tid == 0){
      for (int q = 1; q < NW; ++q){
        mx = fmaxf(mx, rv[q]); mn = fminf(mn, rmn[q]); neg |= sng[q];
      }
      atomicMax(&ws[0], enc_f32(mx));
      atomicMax(&ws[5], ~enc_f32(mn));          // complemented min (init 0)
      if (neg) atomicOr(&ws[1], 1u);
      __threadfence();
      atomicAdd(&ws[3], 1u);                    // publish arrival; spin LATER
    }
  }

  // ---- top-15 on RAW (overlapped with the device barrier wait) ----
  // -inf kept in place: filled < every finite value, so the top-15 multiset of
  // the filled row equals raw top-15 with -inf entries mapped to filled later.
  {
    float lv[RPT];
    #pragma unroll
    for (int j = 0; j < RPT; ++j) lv[j] = raw[j];
    #pragma unroll
    for (int t = 0; t < KK; ++t){
      float bv = lv[0]; int bs = 0;
      #pragma unroll
      for (int j = 1; j < RPT; ++j){ if (lv[j] > bv){ bv = lv[j]; bs = j; } }
      int bidx = (lane << 3) | bs;
      #pragma unroll
      for (int off = 32; off; off >>= 1){
        float ov = __shfl_xor(bv, off);
        int oi = __shfl_xor(bidx, off);
        if (ov > bv || (ov == bv && oi < bidx)){ bv = ov; bidx = oi; }
      }
      if ((bidx >> 3) == lane){
        int s = bidx & 7;
        #pragma unroll
        for (int j = 0; j < RPT; ++j) if (j == s) lv[j] = -INFINITY;
      }
      if (lane == 0) cands[wv * KK + t] = bv;
    }
  }
  __syncthreads();
  if (wv == 0){
    float c0 = (lane < NW * KK) ? cands[lane] : -INFINITY;
    float c1 = (lane + 64 < NW * KK) ? cands[lane + 64] : -INFINITY;
    #pragma unroll
    for (int t = 0; t < KK; ++t){
      int sel = (c0 >= c1) ? 0 : 1;
      float bv = sel ? c1 : c0;
      int bidx = (lane << 1) | sel;
      #pragma unroll
      for (int off = 32; off; off >>= 1){
        float ov = __shfl_xor(bv, off);
        int oi = __shfl_xor(bidx, off);
        if (ov > bv || (ov == bv && oi < bidx)){ bv = ov; bidx = oi; }
      }
      if ((bidx >> 1) == lane){
        if ((bidx & 1) == 0) c0 = -INFINITY; else c1 = -INFINITY;
      }
      if (lane == 0) tk[t] = bv;
    }
  }
  // ---- now spin for the device-wide stats ----
  if (tid == 0){
    while (__hip_atomic_load(&ws[3], __ATOMIC_ACQUIRE, __HIP_MEMORY_SCOPE_AGENT) < (unsigned)NBLK)
      __builtin_amdgcn_s_sleep(2);
    statb[0] = dec_f32(__hip_atomic_load(&ws[0], __ATOMIC_RELAXED, __HIP_MEMORY_SCOPE_AGENT));
    statb[1] = dec_f32(~__hip_atomic_load(&ws[5], __ATOMIC_RELAXED, __HIP_MEMORY_SCOPE_AGENT));
    statb[2] = __hip_atomic_load(&ws[1], __ATOMIC_RELAXED, __HIP_MEMORY_SCOPE_AGENT) ? 1.0f : 0.0f;
  }
  __syncthreads();

  const float smax = statb[0];
  const float smin_raw = statb[1];
  const bool has_neg = statb[2] != 0.0f;
  const float filled = smin_raw - (smax - smin_raw);
  const float smin_eff = has_neg ? filled : smin_raw;
  const float cmax = fmaxf(fmaxf(smin_eff * smin_eff, smax * smax),
                           fmaxf((smin_eff - 15.0f) * (smin_eff - 15.0f),
                                 (smax - 15.0f) * (smax - 15.0f)));
  const float cinv = 1.0f / cmax;
  const float tauv = taup[0];
  const float invtau = 1.0f / tauv;
  const float inv_n = 1.0f / (float)NN;

  // ---- fixed s values: register-resident ----
  float sv[RPT];
  #pragma unroll
  for (int j = 0; j < RPT; ++j){
    float v = raw[j]; if (v == -INFINITY) v = filled;
    sv[j] = v;
  }

  // ---- Gamma0 column sums (all 8 rows; redundant across the pair) ----
  {
    float p[K1];
    float tkr[KK];
    #pragma unroll
    for (int c = 0; c < KK; ++c){
      float tv = tk[c];
      tkr[c] = (tv == -INFINITY) ? filled : tv;
    }
    #pragma unroll
    for (int c = 0; c < K1; ++c) p[c] = 0.0f;
    #pragma unroll
    for (int j = 0; j < RPT; ++j){
      float si = sv[j];
      #pragma unroll
      for (int c = 0; c < KK; ++c){
        float z = fabsf(tkr[c] - si) * invtau;
        float raw1 = __builtin_amdgcn_rcpf(1.0f + __expf(z)) + SMALLC;
        p[c] += raw1;
      }
    }
    block_fold16(p, wbuf, cbuf, lane, wv, tid);
  }

  // ---- warm start via SEPARABLE w2 identity (all 8 rows; redundant) ----
  float colinv_n[KK];
  {
    float pcol[K1];
    float pr0 = 0.0f, pr1 = 0.0f, pr2 = 0.0f, pr3 = 0.0f, pr4 = 0.0f;
    float tkr[KK];
    #pragma unroll
    for (int c = 0; c < KK; ++c){
      float tv = tk[c];
      tkr[c] = (tv == -INFINITY) ? filled : tv;
      colinv_n[c] = (1.0f / cbuf[c]) * inv_n;
    }
    #pragma unroll
    for (int c = 0; c < K1; ++c) pcol[c] = 0.0f;
    #pragma unroll
    for (int j = 0; j < RPT; ++j){
      int i = tid + NT * j;
      float si = sv[j];
      float bb[K1];
      float rowpart = 0.0f;
      #pragma unroll
      for (int c = 0; c < KK; ++c){
        float d = si - (float)(KK - c);
        float Cc = d * d * cinv;
        float z = fabsf(tkr[c] - si) * invtau;
        float raw1 = __builtin_amdgcn_rcpf(1.0f + __expf(z)) + SMALLC;
        float g0 = raw1 * colinv_n[c];
        rowpart += g0;
        bb[c] = Cc + EPSI * __logf(g0);
      }
      {
        float Cc = si * si * cinv;
        float g0l = fminf(fmaxf(inv_n - rowpart, SMALLC), 1.0f - SMALLC);
        bb[KK] = Cc + EPSI * __logf(g0l);
      }
      float rs = 0.0f;
      #pragma unroll
      for (int c = 0; c < K1; ++c){ pcol[c] += bb[c]; rs += bb[c]; }
      const float* w1r = w1 + (size_t)i * 5;
      pr0 = fmaf(w1r[0], rs, pr0);
      pr1 = fmaf(w1r[1], rs, pr1);
      pr2 = fmaf(w1r[2], rs, pr2);
      pr3 = fmaf(w1r[3], rs, pr3);
      pr4 = fmaf(w1r[4], rs, pr4);
    }
    float rcol = wave_fold16(pcol, lane);
    float r0 = full64_sum(pr0);
    float r1 = full64_sum(pr1);
    float r2 = full64_sum(pr2);
    float r3 = full64_sum(pr3);
    float r4 = full64_sum(pr4);
    if (lane < 16) wbuf[wv * K1 + fold_col(lane)] = rcol;
    if (lane == 16) wrow[wv * 5 + 0] = r0;
    if (lane == 17) wrow[wv * 5 + 1] = r1;
    if (lane == 18) wrow[wv * 5 + 2] = r2;
    if (lane == 19) wrow[wv * 5 + 3] = r3;
    if (lane == 20) wrow[wv * 5 + 4] = r4;
    __syncthreads();
    if (tid < 16){
      float t = 0.0f;
      #pragma unroll
      for (int q = 0; q < NW; ++q) t += wbuf[q * K1 + tid];
      bbcol[tid] = t;
    } else if (tid < 21){
      int r = tid - 16;
      float t = 0.0f;
      #pragma unroll
      for (int q = 0; q < NW; ++q) t += wrow[q * 5 + r];
      xbuf[r] = t;
    }
    __syncthreads();
    if (tid < 5){
      float xr = xbuf[tid];
      #pragma unroll
      for (int c = 0; c < KK; ++c)
        xr = fmaf(w1[(size_t)(NN + c) * 5 + tid], bbcol[c], xr);
      xv5[tid] = xr;
    }
    __syncthreads();
  }

  // ---- vt init ----
  float vt[K1];
  {
    float xv[5];
    #pragma unroll
    for (int r = 0; r < 5; ++r) xv[r] = xv5[r];
    #pragma unroll
    for (int c = 0; c < KK; ++c){
      float g = 0.0f;
      #pragma unroll
      for (int r = 0; r < 5; ++r) g += xv[r] * w1[(size_t)(NN + c) * 5 + r];
      float Bc = expf(-10.0f * cinv * (float)((KK - c) * (KK - c)));
      vt[c] = Bc * expf(g * 10.0f);
    }
    vt[KK] = 1.0f;
  }

  // ---- x per row pair + power table ----
  f2 x2[NPAIR];
  #pragma unroll
  for (int q = 0; q < NPAIR; ++q){
    x2[q].x = expf(sv[2 * q] * (-20.0f * cinv));
    x2[q].y = expf(sv[2 * q + 1] * (-20.0f * cinv));
  }
  f2 xp[NPAIR][K1];
  #pragma unroll
  for (int q = 0; q < NPAIR; ++q){
    xp[q][0].x = 1.0f; xp[q][0].y = 1.0f;
    xp[q][1] = x2[q];
    #pragma unroll
    for (int c = 2; c < K1; ++c) xp[q][c] = xp[q][c - 1] * x2[q];
  }

  // ---- Sinkhorn loop (full row; redundant across the pair, no sync) ----
  f2 t2[NPAIR];
  const float nmul = ((lane & 15) < KK) ? 1.0f : 4081.0f;
  float pv2 = 0.0f, pv1 = 0.0f;
  int pcnt = -1;
  #pragma unroll 1
  for (int it = 0; it < NITER; ++it){
    const int ph = it & 1;
    #pragma unroll
    for (int q = 0; q < NPAIR; ++q){
      f2 h; h.x = vt[KK]; h.y = vt[KK];
      #pragma unroll
      for (int c = KK - 1; c >= 0; --c){
        f2 vc; vc.x = vt[c]; vc.y = vt[c];
        h = pk_fma(h, x2[q], vc);
      }
      t2[q].x = __builtin_amdgcn_rcpf(h.x);
      t2[q].y = __builtin_amdgcn_rcpf(h.y);
    }
    float p[K1];
    #pragma unroll
    for (int c = 0; c < K1; ++c){
      f2 s = t2[0] * xp[0][c];
      #pragma unroll
      for (int q = 1; q < NPAIR; ++q) s = pk_fma(t2[q], xp[q][c], s);
      p[c] = s.x + s.y;
    }
    float r = wave_fold16(p, lane);
    if (lane < 16) wbufT[ph][fold_col(lane) * TS + wv] = r;
    __syncthreads();
    float md = -1.0f;
    float wout = 0.0f;
    if (lane < 16){
      const float* wp = &wbufT[ph][lane * TS];
      float4 a4 = *(const float4*)wp;
      float4 b4 = *(const float4*)(wp + 4);
      float t = ((a4.x + a4.y) + (a4.z + a4.w)) + ((b4.x + b4.y) + (b4.z + b4.w));
      float wnew = nmul * __builtin_amdgcn_rcpf(t);
      md = fabsf(wnew - pv1) - CONV_REL * pv1;
      wout = wnew;
    }
    if (pcnt >= 1){
      float r1 = 0.0f, r2 = 0.0f;
      if (lane < 16){
        float winv = __builtin_amdgcn_rcpf(wout);
        r1 = (pv1 - pv2) * winv;
        r2 = (wout - pv1) * winv;
      }
      float s12 = full64_sum(r1 * r2);
      float s11 = full64_sum(r1 * r1);
      float s12b = bcast_lane0(s12);
      float s11b = bcast_lane0(s11);
      int anymove = __any((lane < 16) && (fabsf(r2) > 4.0f * CONV_REL));
      float fac = s12b * __builtin_amdgcn_rcpf(s11b - s12b);
      float acc = wout * (1.0f + r2 * fac);
      int okbr = (lane < 16) ? (acc > 0.1f * wout && acc < 10.0f * wout) : 1;
      int allbr = __all(okbr);
      if ((s12b > 0.0f) && (s12b < 0.97f * s11b) && anymove && allbr){
        if (lane < 16) wout = acc;
        pcnt = -1;
      }
    }
    pcnt++;
    pv2 = pv1; pv1 = wout;
    int conv = __all(md <= 0.0f);
    #pragma unroll
    for (int c = 0; c < K1; ++c)
      vt[c] = __uint_as_float((unsigned)__builtin_amdgcn_readlane(
                  (int)__float_as_uint(wout), c));
    if (conv) break;
  }

  // ---- epilogue: THIS block's half only (q = 2*half, 2*half+1) ----
  float nrm = 0.0f;
  {
    float tkr[KK];
    #pragma unroll
    for (int c = 0; c < KK; ++c){
      float tv = tk[c];
      tkr[c] = (tv == -INFINITY) ? filled : tv;
    }
    #pragma unroll
    for (int qq = 0; qq < 2; ++qq){
      const int q = 2 * half + qq;
      #pragma unroll
      for (int e = 0; e < 2; ++e){
        int i = tid + NT * (2 * q + e);
        float si = sv[2 * q + e];
        float tin = (e ? t2[q].y : t2[q].x) * inv_n;
        float rowpart = 0.0f;
        float gamv[KK];
        float gaml;
        #pragma unroll
        for (int c = 0; c < KK; ++c){
          float xc = e ? xp[q][c].y : xp[q][c].x;
          float gam = (tin * xc) * vt[c];
          float z = fabsf(tkr[c] - si) * invtau;
          float raw1 = __builtin_amdgcn_rcpf(1.0f + __expf(z)) + SMALLC;
          float g0 = raw1 * colinv_n[c];
          rowpart += g0;
          float d = gam - g0;
          nrm += d * d;
          gamv[c] = gam * (float)NN;
        }
        {
          float xc = e ? xp[q][KK].y : xp[q][KK].x;
          gaml = (tin * xc) * vt[KK];
          float g0l = fminf(fmaxf(inv_n - rowpart, SMALLC), 1.0f - SMALLC);
          float d = gaml - g0l;
          nrm += d * d;
        }
        float* op = out + (size_t)(b * NN + i) * KK;
        #pragma unroll
        for (int c = 0; c < KK; ++c) op[c] = gamv[c];
      }
    }
  }
  #pragma unroll
  for (int off = 32; off; off >>= 1) nrm += __shfl_xor(nrm, off);
  if (lane == 0) rv[wv] = nrm;
  __syncthreads();
  if (tid == 0){
    float t = 0.0f;
    for (int q = 0; q < NW; ++q) t += rv[q];
    atomicAdd(reinterpret_cast<float*>(ws) + 2, t);
    __threadfence();
    unsigned prev = atomicAdd(&ws[4], 1u);
    if (prev == (unsigned)(NBLK - 1)){
      float n2 = __hip_atomic_load(reinterpret_cast<float*>(ws) + 2,
                                   __ATOMIC_RELAXED, __HIP_MEMORY_SCOPE_AGENT);
      out[OUT_A_ELEMS] = sqrtf(n2);
    }
  }
}

extern "C" void kernel_launch(void* const* d_in, const int* in_sizes, int n_in,
                              void* d_out, int out_size, void* d_ws, size_t ws_size,
                              hipStream_t stream){
  const float* scores = (const float*)d_in[0];
  const float* tau    = (const float*)d_in[1];
  const float* w1     = (const float*)d_in[2];  // (4111, 5) row-major
  const float* w2     = (const float*)d_in[3];  // (5, 65536) row-major (unused: separable identity)
  float* out = (float*)d_out;
  unsigned* ws = (unsigned*)d_ws;

  // single node: [0]=max_enc 0, [1]=neg 0, [2]=norm 0.f, [3]=arrive 0,
  //              [4]=done 0, [5]=min_enc_complement 0
  hipMemsetAsync(ws, 0x00, 24, stream);

  k_main<<<NBLK, NT, 0, stream>>>(scores, tau, w1, w2, out, ws);
}

// Round 15
// 131.959 us; speedup vs baseline: 2.0385x; 1.2920x over previous
//
#include <hip/hip_runtime.h>
#include <math.h>

#define KK 15
#define K1 16
#define NN 4096
#define BSZ 128
#define NT 512
#define RPT 8          // rows per thread = NN/NT
#define NPAIR 4        // packed row pairs per thread
#define NW 8           // waves per block
#define EPSI 0.1f
#define SMALLC 1e-20f
#define NITER 100      // cap; conv exit fires after only a few iters (R11 evidence)
#define OUT_A_ELEMS (BSZ * NN * KK)
#define TS 20          // wbufT row stride in floats (2-way bank alias only, free)
#define CONV_REL 2e-6f

typedef __attribute__((ext_vector_type(2))) float f2;
typedef __attribute__((ext_vector_type(2))) unsigned u2v;
__device__ __forceinline__ f2 pk_fma(f2 a, f2 b, f2 c){
  return __builtin_elementwise_fma(a, b, c);
}

// ---------- sortable float <-> uint encoding for atomic min/max ----------
// max: enc as-is. min: stored COMPLEMENTED so the all-zero init works for both.
__device__ __forceinline__ unsigned enc_f32(float f){
  unsigned u = __float_as_uint(f);
  return (u & 0x80000000u) ? ~u : (u | 0x80000000u);
}
__device__ __forceinline__ float dec_f32(unsigned e){
  unsigned u = (e & 0x80000000u) ? (e ^ 0x80000000u) : ~e;
  return __uint_as_float(u);
}

// ws layout (uint32): [0]=max_enc(0) [1]=neg_flag(0) [2]=norm^2 f32(0)
//                     [3]=arrive(0) [4]=done(0) [5]=min_enc_complement(0)

// ---------- DPP cross-lane mov (VALU pipe, not DS) ----------
template<int CTRL>
__device__ __forceinline__ float dpp_movf(float x){
  return __uint_as_float((unsigned)__builtin_amdgcn_update_dpp(
      (int)0, (int)__float_as_uint(x), CTRL, 0xF, 0xF, true));
}

__device__ __forceinline__ float bcast_lane0(float x){
  return __uint_as_float((unsigned)__builtin_amdgcn_readlane(
      (int)__float_as_uint(x), 0));
}

__device__ __forceinline__ float xsum16(float r){
#if __has_builtin(__builtin_amdgcn_permlane16_swap)
  u2v s = __builtin_amdgcn_permlane16_swap(__float_as_uint(r), __float_as_uint(r), false, false);
  return __uint_as_float(s.x) + __uint_as_float(s.y);
#else
  return r + __shfl_xor(r, 16);
#endif
}
__device__ __forceinline__ float xsum32(float r){
#if __has_builtin(__builtin_amdgcn_permlane32_swap)
  u2v s = __builtin_amdgcn_permlane32_swap(__float_as_uint(r), __float_as_uint(r), false, false);
  return __uint_as_float(s.x) + __uint_as_float(s.y);
#else
  return r + __shfl_xor(r, 32);
#endif
}

// 16-lane-group sum -- 4 DPP adds, no DS
__device__ __forceinline__ float sum16_all(float v){
  v += dpp_movf<0x128>(v);   // row_ror:8
  v += dpp_movf<0x124>(v);   // row_ror:4
  v += dpp_movf<0x4E>(v);    // quad_perm xor2
  v += dpp_movf<0xB1>(v);    // quad_perm xor1
  return v;
}
// full 64-lane sum in every lane -- all VALU, no DS
__device__ __forceinline__ float full64_sum(float v){
  return xsum32(xsum16(sum16_all(v)));
}

// ---------- 16-column lane-fold reduction (DPP-based) ----------
__device__ __forceinline__ int fold_col(int lane){
  int l = lane & 15;
  return ((l & 1) << 3) | ((l & 2) << 1) | ((l & 8) >> 2) | ((l & 4) >> 2);
}

__device__ __forceinline__ float wave_fold16(const float p[K1], int lane){
  float a[8];
  {
    const bool hi = (lane & 1) != 0;
    #pragma unroll
    for (int j = 0; j < 8; ++j){
      float send = hi ? p[j] : p[j + 8];
      float keep = hi ? p[j + 8] : p[j];
      a[j] = keep + dpp_movf<0xB1>(send);
    }
  }
  float bq[4];
  {
    const bool hi = (lane & 2) != 0;
    #pragma unroll
    for (int j = 0; j < 4; ++j){
      float send = hi ? a[j] : a[j + 4];
      float keep = hi ? a[j + 4] : a[j];
      bq[j] = keep + dpp_movf<0x4E>(send);
    }
  }
  float cq[2];
  {
    const bool hi = (lane & 8) != 0;
    float s0 = hi ? bq[0] : bq[2];
    float s1 = hi ? bq[1] : bq[3];
    float k0 = hi ? bq[2] : bq[0];
    float k1 = hi ? bq[3] : bq[1];
    cq[0] = k0 + dpp_movf<0x128>(s0);
    cq[1] = k1 + dpp_movf<0x128>(s1);
  }
  float r;
  {
    const bool hi = (lane & 4) != 0;
    float send = hi ? cq[0] : cq[1];
    float keep = hi ? cq[1] : cq[0];
    r = keep + __shfl_xor(send, 4);
  }
  r = xsum16(r);
  r = xsum32(r);
  return r;
}

__device__ __forceinline__ void block_fold16(const float p[K1], float* wb, float* tb,
                                             int lane, int wv, int tid){
  float r = wave_fold16(p, lane);
  if (lane < 16) wb[wv * K1 + fold_col(lane)] = r;
  __syncthreads();
  if (tid < 16){
    float t = 0.0f;
    #pragma unroll
    for (int q = 0; q < NW; ++q) t += wb[q * K1 + tid];
    tb[tid] = t;
  }
  __syncthreads();
}

__global__ __launch_bounds__(NT, 2) void k_main(
    const float* __restrict__ scores, const float* __restrict__ taup,
    const float* __restrict__ w1, const float* __restrict__ w2,
    float* __restrict__ out, unsigned* __restrict__ ws){
  const int b = blockIdx.x;
  const int tid = threadIdx.x;
  const int lane = tid & 63;
  const int wv = tid >> 6;

  __shared__ float tk[KK];
  __shared__ float cands[NW * KK];
  __shared__ __align__(16) float cbuf[K1];
  __shared__ float wbuf[NW * K1];
  __shared__ float wrow[NW * 5];
  __shared__ __align__(16) float xbuf[K1];
  __shared__ __align__(16) float bbcol[K1];
  __shared__ float xv5[8];
  __shared__ __align__(16) float wbufT[2][K1 * TS];
  __shared__ __align__(16) float stg[NW][64 * KK];   // 30 KB wave-private store stage
  __shared__ float rv[NW];
  __shared__ float rmn[NW];
  __shared__ unsigned sng[NW];
  __shared__ float statb[4];

  // ---- load raw row ----
  float raw[RPT];
  #pragma unroll
  for (int j = 0; j < RPT; ++j) raw[j] = scores[(size_t)b * NN + tid + NT * j];

  // ---- stats: reduce + PUBLISH (no spin yet) ----
  {
    float mx = -INFINITY, mn = INFINITY; unsigned neg = 0u;
    #pragma unroll
    for (int j = 0; j < RPT; ++j){
      float v = raw[j];
      mx = fmaxf(mx, v);
      if (v == -INFINITY) neg = 1u; else mn = fminf(mn, v);
    }
    #pragma unroll
    for (int off = 32; off; off >>= 1){
      mx = fmaxf(mx, __shfl_xor(mx, off));
      mn = fminf(mn, __shfl_xor(mn, off));
      neg |= (unsigned)__shfl_xor((int)neg, off);
    }
    if (lane == 0){ rv[wv] = mx; rmn[wv] = mn; sng[wv] = neg; }
    __syncthreads();
    if (tid == 0){
      for (int q = 1; q < NW; ++q){
        mx = fmaxf(mx, rv[q]); mn = fminf(mn, rmn[q]); neg |= sng[q];
      }
      atomicMax(&ws[0], enc_f32(mx));
      atomicMax(&ws[5], ~enc_f32(mn));          // complemented min (init 0)
      if (neg) atomicOr(&ws[1], 1u);
      __threadfence();
      atomicAdd(&ws[3], 1u);                    // publish arrival; spin LATER
    }
  }

  // ---- top-15 on RAW (overlapped with the device barrier wait) ----
  // -inf kept in place: filled <= every finite value, so the filled-row top-15
  // equals raw top-15 with -inf entries mapped to filled at use sites.
  {
    float lv[RPT];
    #pragma unroll
    for (int j = 0; j < RPT; ++j) lv[j] = raw[j];
    #pragma unroll
    for (int t = 0; t < KK; ++t){
      float bv = lv[0]; int bs = 0;
      #pragma unroll
      for (int j = 1; j < RPT; ++j){ if (lv[j] > bv){ bv = lv[j]; bs = j; } }
      int bidx = (lane << 3) | bs;
      #pragma unroll
      for (int off = 32; off; off >>= 1){
        float ov = __shfl_xor(bv, off);
        int oi = __shfl_xor(bidx, off);
        if (ov > bv || (ov == bv && oi < bidx)){ bv = ov; bidx = oi; }
      }
      if ((bidx >> 3) == lane){
        int s = bidx & 7;
        #pragma unroll
        for (int j = 0; j < RPT; ++j) if (j == s) lv[j] = -INFINITY;
      }
      if (lane == 0) cands[wv * KK + t] = bv;
    }
  }
  __syncthreads();
  if (wv == 0){
    float c0 = (lane < NW * KK) ? cands[lane] : -INFINITY;
    float c1 = (lane + 64 < NW * KK) ? cands[lane + 64] : -INFINITY;
    #pragma unroll
    for (int t = 0; t < KK; ++t){
      int sel = (c0 >= c1) ? 0 : 1;
      float bv = sel ? c1 : c0;
      int bidx = (lane << 1) | sel;
      #pragma unroll
      for (int off = 32; off; off >>= 1){
        float ov = __shfl_xor(bv, off);
        int oi = __shfl_xor(bidx, off);
        if (ov > bv || (ov == bv && oi < bidx)){ bv = ov; bidx = oi; }
      }
      if ((bidx >> 1) == lane){
        if ((bidx & 1) == 0) c0 = -INFINITY; else c1 = -INFINITY;
      }
      if (lane == 0) tk[t] = bv;
    }
  }
  // ---- now spin for the device-wide stats ----
  if (tid == 0){
    while (__hip_atomic_load(&ws[3], __ATOMIC_ACQUIRE, __HIP_MEMORY_SCOPE_AGENT) < (unsigned)BSZ)
      __builtin_amdgcn_s_sleep(2);
    statb[0] = dec_f32(__hip_atomic_load(&ws[0], __ATOMIC_RELAXED, __HIP_MEMORY_SCOPE_AGENT));
    statb[1] = dec_f32(~__hip_atomic_load(&ws[5], __ATOMIC_RELAXED, __HIP_MEMORY_SCOPE_AGENT));
    statb[2] = __hip_atomic_load(&ws[1], __ATOMIC_RELAXED, __HIP_MEMORY_SCOPE_AGENT) ? 1.0f : 0.0f;
  }
  __syncthreads();

  const float smax = statb[0];
  const float smin_raw = statb[1];
  const bool has_neg = statb[2] != 0.0f;
  const float filled = smin_raw - (smax - smin_raw);
  const float smin_eff = has_neg ? filled : smin_raw;
  const float cmax = fmaxf(fmaxf(smin_eff * smin_eff, smax * smax),
                           fmaxf((smin_eff - 15.0f) * (smin_eff - 15.0f),
                                 (smax - 15.0f) * (smax - 15.0f)));
  const float cinv = 1.0f / cmax;
  const float tauv = taup[0];
  const float invtau = 1.0f / tauv;
  const float inv_n = 1.0f / (float)NN;

  // ---- fixed s values: register-resident ----
  float sv[RPT];
  #pragma unroll
  for (int j = 0; j < RPT; ++j){
    float v = raw[j]; if (v == -INFINITY) v = filled;
    sv[j] = v;
  }

  // ---- Gamma0 column sums ----
  {
    float p[K1];
    float tkr[KK];
    #pragma unroll
    for (int c = 0; c < KK; ++c){
      float tv = tk[c];
      tkr[c] = (tv == -INFINITY) ? filled : tv;
    }
    #pragma unroll
    for (int c = 0; c < K1; ++c) p[c] = 0.0f;
    #pragma unroll
    for (int j = 0; j < RPT; ++j){
      float si = sv[j];
      #pragma unroll
      for (int c = 0; c < KK; ++c){
        float z = fabsf(tkr[c] - si) * invtau;
        float raw1 = __builtin_amdgcn_rcpf(1.0f + __expf(z)) + SMALLC;
        p[c] += raw1;
      }
    }
    block_fold16(p, wbuf, cbuf, lane, wv, tid);
  }

  // ---- warm start via SEPARABLE w2 identity (fused fold: 3 barriers) ----
  float colinv_n[KK];
  {
    float pcol[K1];
    float pr0 = 0.0f, pr1 = 0.0f, pr2 = 0.0f, pr3 = 0.0f, pr4 = 0.0f;
    float tkr[KK];
    #pragma unroll
    for (int c = 0; c < KK; ++c){
      float tv = tk[c];
      tkr[c] = (tv == -INFINITY) ? filled : tv;
      colinv_n[c] = (1.0f / cbuf[c]) * inv_n;
    }
    #pragma unroll
    for (int c = 0; c < K1; ++c) pcol[c] = 0.0f;
    #pragma unroll
    for (int j = 0; j < RPT; ++j){
      int i = tid + NT * j;
      float si = sv[j];
      float bb[K1];
      float rowpart = 0.0f;
      #pragma unroll
      for (int c = 0; c < KK; ++c){
        float d = si - (float)(KK - c);
        float Cc = d * d * cinv;
        float z = fabsf(tkr[c] - si) * invtau;
        float raw1 = __builtin_amdgcn_rcpf(1.0f + __expf(z)) + SMALLC;
        float g0 = raw1 * colinv_n[c];
        rowpart += g0;
        bb[c] = Cc + EPSI * __logf(g0);
      }
      {
        float Cc = si * si * cinv;
        float g0l = fminf(fmaxf(inv_n - rowpart, SMALLC), 1.0f - SMALLC);
        bb[KK] = Cc + EPSI * __logf(g0l);
      }
      float rs = 0.0f;
      #pragma unroll
      for (int c = 0; c < K1; ++c){ pcol[c] += bb[c]; rs += bb[c]; }
      const float* w1r = w1 + (size_t)i * 5;
      pr0 = fmaf(w1r[0], rs, pr0);
      pr1 = fmaf(w1r[1], rs, pr1);
      pr2 = fmaf(w1r[2], rs, pr2);
      pr3 = fmaf(w1r[3], rs, pr3);
      pr4 = fmaf(w1r[4], rs, pr4);
    }
    float rcol = wave_fold16(pcol, lane);
    float r0 = full64_sum(pr0);
    float r1 = full64_sum(pr1);
    float r2 = full64_sum(pr2);
    float r3 = full64_sum(pr3);
    float r4 = full64_sum(pr4);
    if (lane < 16) wbuf[wv * K1 + fold_col(lane)] = rcol;
    if (lane == 16) wrow[wv * 5 + 0] = r0;
    if (lane == 17) wrow[wv * 5 + 1] = r1;
    if (lane == 18) wrow[wv * 5 + 2] = r2;
    if (lane == 19) wrow[wv * 5 + 3] = r3;
    if (lane == 20) wrow[wv * 5 + 4] = r4;
    __syncthreads();
    if (tid < 16){
      float t = 0.0f;
      #pragma unroll
      for (int q = 0; q < NW; ++q) t += wbuf[q * K1 + tid];
      bbcol[tid] = t;
    } else if (tid < 21){
      int r = tid - 16;
      float t = 0.0f;
      #pragma unroll
      for (int q = 0; q < NW; ++q) t += wrow[q * 5 + r];
      xbuf[r] = t;
    }
    __syncthreads();
    if (tid < 5){
      float xr = xbuf[tid];
      #pragma unroll
      for (int c = 0; c < KK; ++c)
        xr = fmaf(w1[(size_t)(NN + c) * 5 + tid], bbcol[c], xr);
      xv5[tid] = xr;
    }
    __syncthreads();
  }

  // ---- vt init ----
  float vt[K1];
  {
    float xv[5];
    #pragma unroll
    for (int r = 0; r < 5; ++r) xv[r] = xv5[r];
    #pragma unroll
    for (int c = 0; c < KK; ++c){
      float g = 0.0f;
      #pragma unroll
      for (int r = 0; r < 5; ++r) g += xv[r] * w1[(size_t)(NN + c) * 5 + r];
      float Bc = expf(-10.0f * cinv * (float)((KK - c) * (KK - c)));
      vt[c] = Bc * expf(g * 10.0f);
    }
    vt[KK] = 1.0f;
  }

  // ---- x per row pair + power table ----
  f2 x2[NPAIR];
  #pragma unroll
  for (int q = 0; q < NPAIR; ++q){
    x2[q].x = expf(sv[2 * q] * (-20.0f * cinv));
    x2[q].y = expf(sv[2 * q + 1] * (-20.0f * cinv));
  }
  f2 xp[NPAIR][K1];
  #pragma unroll
  for (int q = 0; q < NPAIR; ++q){
    xp[q][0].x = 1.0f; xp[q][0].y = 1.0f;
    xp[q][1] = x2[q];
    #pragma unroll
    for (int c = 2; c < K1; ++c) xp[q][c] = xp[q][c - 1] * x2[q];
  }

  // ---- Sinkhorn: synchronized loop + shared-lambda Anderson + conv exit ----
  f2 t2[NPAIR];
  const float nmul = ((lane & 15) < KK) ? 1.0f : 4081.0f;
  float pv2 = 0.0f, pv1 = 0.0f;
  int pcnt = -1;
  #pragma unroll 1
  for (int it = 0; it < NITER; ++it){
    const int ph = it & 1;
    #pragma unroll
    for (int q = 0; q < NPAIR; ++q){
      f2 h; h.x = vt[KK]; h.y = vt[KK];
      #pragma unroll
      for (int c = KK - 1; c >= 0; --c){
        f2 vc; vc.x = vt[c]; vc.y = vt[c];
        h = pk_fma(h, x2[q], vc);
      }
      t2[q].x = __builtin_amdgcn_rcpf(h.x);
      t2[q].y = __builtin_amdgcn_rcpf(h.y);
    }
    float p[K1];
    #pragma unroll
    for (int c = 0; c < K1; ++c){
      f2 s = t2[0] * xp[0][c];
      #pragma unroll
      for (int q = 1; q < NPAIR; ++q) s = pk_fma(t2[q], xp[q][c], s);
      p[c] = s.x + s.y;
    }
    float r = wave_fold16(p, lane);
    if (lane < 16) wbufT[ph][fold_col(lane) * TS + wv] = r;
    __syncthreads();
    float md = -1.0f;
    float wout = 0.0f;
    if (lane < 16){
      const float* wp = &wbufT[ph][lane * TS];
      float4 a4 = *(const float4*)wp;
      float4 b4 = *(const float4*)(wp + 4);
      float t = ((a4.x + a4.y) + (a4.z + a4.w)) + ((b4.x + b4.y) + (b4.z + b4.w));
      float wnew = nmul * __builtin_amdgcn_rcpf(t);
      md = fabsf(wnew - pv1) - CONV_REL * pv1;
      wout = wnew;
    }
    if (pcnt >= 1){
      float r1 = 0.0f, r2 = 0.0f;
      if (lane < 16){
        float winv = __builtin_amdgcn_rcpf(wout);
        r1 = (pv1 - pv2) * winv;
        r2 = (wout - pv1) * winv;
      }
      float s12 = full64_sum(r1 * r2);
      float s11 = full64_sum(r1 * r1);
      float s12b = bcast_lane0(s12);
      float s11b = bcast_lane0(s11);
      int anymove = __any((lane < 16) && (fabsf(r2) > 4.0f * CONV_REL));
      float fac = s12b * __builtin_amdgcn_rcpf(s11b - s12b);
      float acc = wout * (1.0f + r2 * fac);
      int okbr = (lane < 16) ? (acc > 0.1f * wout && acc < 10.0f * wout) : 1;
      int allbr = __all(okbr);
      if ((s12b > 0.0f) && (s12b < 0.97f * s11b) && anymove && allbr){
        if (lane < 16) wout = acc;
        pcnt = -1;
      }
    }
    pcnt++;
    pv2 = pv1; pv1 = wout;
    int conv = __all(md <= 0.0f);
    #pragma unroll
    for (int c = 0; c < K1; ++c)
      vt[c] = __uint_as_float((unsigned)__builtin_amdgcn_readlane(
                  (int)__float_as_uint(wout), c));
    if (conv) break;
  }

  // ---- epilogue: compute -> wave-private LDS stage -> COALESCED stores ----
  // Wave wv, row-block r covers rows [NT*r + 64*wv, +64): 960 contiguous out
  // floats, base 16B-aligned. Same-wave LDS write->read needs no barrier.
  float nrm = 0.0f;
  {
    float tkr[KK];
    #pragma unroll
    for (int c = 0; c < KK; ++c){
      float tv = tk[c];
      tkr[c] = (tv == -INFINITY) ? filled : tv;
    }
    float* stgw = &stg[wv][0];
    #pragma unroll
    for (int q = 0; q < NPAIR; ++q){
      #pragma unroll
      for (int e = 0; e < 2; ++e){
        const int r = 2 * q + e;
        float si = sv[r];
        float tin = (e ? t2[q].y : t2[q].x) * inv_n;
        float rowpart = 0.0f;
        #pragma unroll
        for (int c = 0; c < KK; ++c){
          float xc = e ? xp[q][c].y : xp[q][c].x;
          float gam = (tin * xc) * vt[c];
          float z = fabsf(tkr[c] - si) * invtau;
          float raw1 = __builtin_amdgcn_rcpf(1.0f + __expf(z)) + SMALLC;
          float g0 = raw1 * colinv_n[c];
          rowpart += g0;
          float d = gam - g0;
          nrm += d * d;
          stgw[lane * KK + c] = gam * (float)NN;    // stride-15: 2-way bank alias, free
        }
        {
          float xc = e ? xp[q][KK].y : xp[q][KK].x;
          float gaml = (tin * xc) * vt[KK];
          float g0l = fminf(fmaxf(inv_n - rowpart, SMALLC), 1.0f - SMALLC);
          float d = gaml - g0l;
          nrm += d * d;
        }
        // coalesced writeback: 960 floats = 3x float4 + 1x float2 + 1x float
        float* op = out + ((size_t)b * NN + (size_t)NT * r + 64 * wv) * KK;
        #pragma unroll
        for (int k = 0; k < 3; ++k){
          float4 v = *(const float4*)&stgw[k * 256 + lane * 4];
          *(float4*)&op[k * 256 + lane * 4] = v;
        }
        {
          float2 v2 = *(const float2*)&stgw[768 + lane * 2];
          *(float2*)&op[768 + lane * 2] = v2;
        }
        op[896 + lane] = stgw[896 + lane];
      }
    }
  }
  #pragma unroll
  for (int off = 32; off; off >>= 1) nrm += __shfl_xor(nrm, off);
  if (lane == 0) rv[wv] = nrm;
  __syncthreads();
  if (tid == 0){
    float t = 0.0f;
    for (int q = 0; q < NW; ++q) t += rv[q];
    atomicAdd(reinterpret_cast<float*>(ws) + 2, t);
    __threadfence();
    unsigned prev = atomicAdd(&ws[4], 1u);
    if (prev == (unsigned)(BSZ - 1)){
      float n2 = __hip_atomic_load(reinterpret_cast<float*>(ws) + 2,
                                   __ATOMIC_RELAXED, __HIP_MEMORY_SCOPE_AGENT);
      out[OUT_A_ELEMS] = sqrtf(n2);
    }
  }
}

extern "C" void kernel_launch(void* const* d_in, const int* in_sizes, int n_in,
                              void* d_out, int out_size, void* d_ws, size_t ws_size,
                              hipStream_t stream){
  const float* scores = (const float*)d_in[0];
  const float* tau    = (const float*)d_in[1];
  const float* w1     = (const float*)d_in[2];  // (4111, 5) row-major
  const float* w2     = (const float*)d_in[3];  // (5, 65536) row-major (unused: separable identity)
  float* out = (float*)d_out;
  unsigned* ws = (unsigned*)d_ws;

  // single node: [0]=max_enc 0, [1]=neg 0, [2]=norm 0.f, [3]=arrive 0,
  //              [4]=done 0, [5]=min_enc_complement 0
  hipMemsetAsync(ws, 0x00, 24, stream);

  k_main<<<BSZ, NT, 0, stream>>>(scores, tau, w1, w2, out, ws);
}